// Round 1
// baseline (446.052 us; speedup 1.0000x reference)
//
#include <hip/hip_runtime.h>

// Problem constants
#define BB   2
#define NN   4096
#define CC   512
#define HH   8
#define DD   64
#define MR   8192          // B*N rows
#define NC3  1536          // 3*C
#define PS   4194304       // per-part stride in qkv buffer = B*H*N*D

typedef __attribute__((ext_vector_type(8))) short short8;
typedef __attribute__((ext_vector_type(4))) float floatx4;

__device__ inline unsigned short f2bf(float f) {
  unsigned int u = __float_as_uint(f);
  u = (u + 0x7fffu + ((u >> 16) & 1u)) >> 16;
  return (unsigned short)u;
}

__device__ inline floatx4 fzero4() { floatx4 z = {0.f, 0.f, 0.f, 0.f}; return z; }

// ---------------------------------------------------------------------------
// Kernel 0: convert + transpose w_qkv [512,1536] fp32 -> wt [1536,512] bf16
// ---------------------------------------------------------------------------
__global__ void convert_w_kernel(const float* __restrict__ w, unsigned short* __restrict__ wt) {
  int tid = blockIdx.x * 256 + threadIdx.x;   // [0, 1536*512)
  int n = tid >> 9;                            // col of w / row of wt
  int k = tid & 511;
  wt[tid] = f2bf(w[k * NC3 + n]);
}

// ---------------------------------------------------------------------------
// Kernel 1: pre-LayerNorm. One block per row (C=512), 256 threads x float2.
// Writes fp32 xn (residual) and bf16 xn (GEMM input).
// ---------------------------------------------------------------------------
__global__ void pre_ln_kernel(const float* __restrict__ x, const float* __restrict__ g,
                              const float* __restrict__ be, float* __restrict__ xn,
                              unsigned short* __restrict__ xnb) {
  int row = blockIdx.x;
  const float2* xr = (const float2*)(x + (size_t)row * CC);
  float2 v = xr[threadIdx.x];
  float s  = v.x + v.y;
  float sq = v.x * v.x + v.y * v.y;
  __shared__ float sm[10];
  for (int off = 32; off; off >>= 1) {
    s  += __shfl_down(s,  off, 64);
    sq += __shfl_down(sq, off, 64);
  }
  int w = threadIdx.x >> 6;
  if ((threadIdx.x & 63) == 0) { sm[w] = s; sm[4 + w] = sq; }
  __syncthreads();
  if (threadIdx.x == 0) {
    sm[8] = sm[0] + sm[1] + sm[2] + sm[3];
    sm[9] = sm[4] + sm[5] + sm[6] + sm[7];
  }
  __syncthreads();
  float mean = sm[8] * (1.0f / CC);
  float var  = sm[9] * (1.0f / CC) - mean * mean;
  float rstd = rsqrtf(var + 1e-5f);
  int i0 = threadIdx.x * 2, i1 = i0 + 1;
  float a = (v.x - mean) * rstd * g[i0] + be[i0];
  float b = (v.y - mean) * rstd * g[i1] + be[i1];
  size_t base = (size_t)row * CC;
  xn[base + i0] = a;          xn[base + i1] = b;
  xnb[base + i0] = f2bf(a);   xnb[base + i1] = f2bf(b);
}

// ---------------------------------------------------------------------------
// Kernel 2: QKV GEMM. xn_bf16 [8192,512] @ wt^T -> qkv, 128x128 tiles, BK=64,
// 4 waves in 2x2, each wave 64x64 via 4x4 16x16x32 bf16 MFMA tiles.
// Epilogue scatters: Q (scaled 1/8), K as [B,H,N,D]; V as [B,H,D,N].
// ---------------------------------------------------------------------------
__global__ __launch_bounds__(256) void qkv_gemm_kernel(
    const unsigned short* __restrict__ xnb, const unsigned short* __restrict__ wt,
    const float* __restrict__ bias, unsigned short* __restrict__ qkvb) {
  __shared__ __align__(16) short As[128][72];   // pad 64->72 shorts: 2-way only
  __shared__ __align__(16) short Bs[128][72];
  int tn = blockIdx.x;          // 0..11
  int tm = blockIdx.y;          // 0..63
  int tid = threadIdx.x;
  int wv = tid >> 6, lane = tid & 63;
  int quad = lane >> 4, l16 = lane & 15;
  int wm = wv >> 1, wn = wv & 1;

  floatx4 acc[4][4];
  for (int i = 0; i < 4; i++) for (int j = 0; j < 4; j++) acc[i][j] = fzero4();

  for (int k0 = 0; k0 < 512; k0 += 64) {
    for (int it = 0; it < 4; it++) {
      int c = it * 256 + tid;              // 0..1023
      int row = c >> 3, col8 = (c & 7) * 8;
      *(uint4*)&As[row][col8] = *(const uint4*)&xnb[(size_t)(tm * 128 + row) * 512 + k0 + col8];
      *(uint4*)&Bs[row][col8] = *(const uint4*)&wt[(size_t)(tn * 128 + row) * 512 + k0 + col8];
    }
    __syncthreads();
    for (int kk = 0; kk < 64; kk += 32) {
      short8 a[4], b[4];
      for (int mt = 0; mt < 4; mt++)
        a[mt] = *(const short8*)&As[wm * 64 + mt * 16 + l16][kk + quad * 8];
      for (int nt = 0; nt < 4; nt++)
        b[nt] = *(const short8*)&Bs[wn * 64 + nt * 16 + l16][kk + quad * 8];
      for (int mt = 0; mt < 4; mt++)
        for (int nt = 0; nt < 4; nt++)
          acc[mt][nt] = __builtin_amdgcn_mfma_f32_16x16x32_bf16(a[mt], b[nt], acc[mt][nt], 0, 0, 0);
    }
    __syncthreads();
  }

  for (int mt = 0; mt < 4; mt++) {
    int gm = tm * 128 + wm * 64 + mt * 16 + quad * 4;   // +r below
    int bidx = gm >> 12;                                 // batch (tile never crosses 4096)
    for (int nt = 0; nt < 4; nt++) {
      int gj = tn * 128 + wn * 64 + nt * 16 + l16;       // output col in [0,1536)
      int part = gj >> 9, cc = gj & 511;
      int h = cc >> 6, d = cc & 63;
      float bv = bias[gj];
      for (int r = 0; r < 4; r++) {
        int tok = (gm + r) & 4095;
        float v = acc[mt][nt][r] + bv;
        size_t idx;
        if (part == 0) {        // Q: [B,H,N,D], pre-scale by 1/sqrt(D)=0.125
          v *= 0.125f;
          idx = ((size_t)((bidx * 8 + h) * 4096 + tok)) * 64 + d;
        } else if (part == 1) { // K: [B,H,N,D]
          idx = (size_t)PS + ((size_t)((bidx * 8 + h) * 4096 + tok)) * 64 + d;
        } else {                // V: [B,H,D,N]  (pre-transposed for PV MFMA)
          idx = 2 * (size_t)PS + ((size_t)((bidx * 8 + h) * 64 + d)) * 4096 + tok;
        }
        qkvb[idx] = f2bf(v);
      }
    }
  }
}

// ---------------------------------------------------------------------------
// Kernel 3: flash attention. Grid (64 q-tiles, 16 bh). 256 thr = 4 waves,
// each wave owns 16 q-rows. K-tiles of 128 keys, 32 iterations.
// ---------------------------------------------------------------------------
__global__ __launch_bounds__(256) void attn_kernel(const unsigned short* __restrict__ qkvb,
                                                   float* __restrict__ val) {
  __shared__ __align__(16) short Ks[128][72];      // K tile [key][d], pad 72
  __shared__ __align__(16) short Vt[64][136];      // V^T tile [d][key], pad 136
  __shared__ __align__(16) short Ps[4][16][136];   // wave-private P [qrow][key]
  int bh = blockIdx.y;
  int qb = blockIdx.x * 64;
  int tid = threadIdx.x;
  int wv = tid >> 6, lane = tid & 63, quad = lane >> 4, l16 = lane & 15;
  const unsigned short* Qg = qkvb + (size_t)bh * NN * DD;
  const unsigned short* Kg = qkvb + (size_t)PS + (size_t)bh * NN * DD;
  const unsigned short* Vg = qkvb + 2 * (size_t)PS + (size_t)bh * DD * NN;

  // Stage Q tile (64x64) into Ks[0..63], pull A-fragments to registers.
  for (int it = 0; it < 2; it++) {
    int c = it * 256 + tid;                 // 0..511
    int row = c >> 3, col8 = (c & 7) * 8;
    *(uint4*)&Ks[row][col8] = *(const uint4*)&Qg[(size_t)(qb + row) * 64 + col8];
  }
  __syncthreads();
  short8 qf[2];
  for (int kk = 0; kk < 2; kk++)
    qf[kk] = *(const short8*)&Ks[wv * 16 + l16][kk * 32 + quad * 8];

  floatx4 o[4];
  for (int i = 0; i < 4; i++) o[i] = fzero4();
  float mrow[4], lrow[4];
  for (int r = 0; r < 4; r++) { mrow[r] = -1e30f; lrow[r] = 0.0f; }

  for (int kt = 0; kt < 32; kt++) {
    __syncthreads();   // previous iter's LDS consumers done (also guards Q frag reads)
    for (int it = 0; it < 4; it++) {
      int c = it * 256 + tid;               // 0..1023
      int row = c >> 3, col8 = (c & 7) * 8;
      *(uint4*)&Ks[row][col8] = *(const uint4*)&Kg[(size_t)(kt * 128 + row) * 64 + col8];
      int d = c >> 4, kc8 = (c & 15) * 8;
      *(uint4*)&Vt[d][kc8] = *(const uint4*)&Vg[(size_t)d * NN + kt * 128 + kc8];
    }
    __syncthreads();

    // S = Q K^T  (scale folded into Q). 8 n-tiles of 16 keys.
    floatx4 s[8];
    for (int nt = 0; nt < 8; nt++) {
      s[nt] = fzero4();
      for (int kk = 0; kk < 2; kk++) {
        short8 kf = *(const short8*)&Ks[nt * 16 + l16][kk * 32 + quad * 8];
        s[nt] = __builtin_amdgcn_mfma_f32_16x16x32_bf16(qf[kk], kf, s[nt], 0, 0, 0);
      }
    }

    // Online softmax. C-layout: row = quad*4+r, col = nt*16 + l16.
    for (int r = 0; r < 4; r++) {
      float mx = s[0][r];
      for (int nt = 1; nt < 8; nt++) mx = fmaxf(mx, s[nt][r]);
      for (int off = 1; off < 16; off <<= 1) mx = fmaxf(mx, __shfl_xor(mx, off, 64));
      float mnew = fmaxf(mrow[r], mx);
      float alpha = __expf(mrow[r] - mnew);
      mrow[r] = mnew;
      float sum = 0.0f;
      for (int nt = 0; nt < 8; nt++) {
        float p = __expf(s[nt][r] - mnew);
        s[nt][r] = p;
        sum += p;
      }
      for (int off = 1; off < 16; off <<= 1) sum += __shfl_xor(sum, off, 64);
      lrow[r] = lrow[r] * alpha + sum;
      for (int dt = 0; dt < 4; dt++) o[dt][r] *= alpha;
    }
    // P: C-layout -> LDS (bf16), then read back in A-layout.
    for (int r = 0; r < 4; r++)
      for (int nt = 0; nt < 8; nt++)
        Ps[wv][quad * 4 + r][nt * 16 + l16] = (short)f2bf(s[nt][r]);
    __syncthreads();   // conservative wave-visibility fence (Ps is wave-private)

    // O += P V : 4 d-tiles, K-dim = 128 keys in 4 chunks of 32.
    for (int ks = 0; ks < 4; ks++) {
      short8 pa = *(const short8*)&Ps[wv][l16][ks * 32 + quad * 8];
      for (int dt = 0; dt < 4; dt++) {
        short8 vb = *(const short8*)&Vt[dt * 16 + l16][ks * 32 + quad * 8];
        o[dt] = __builtin_amdgcn_mfma_f32_16x16x32_bf16(pa, vb, o[dt], 0, 0, 0);
      }
    }
  }

  // Epilogue: O /= l, write to val [B,N,C] fp32.
  int b = bh >> 3, h = bh & 7;
  for (int r = 0; r < 4; r++) {
    float inv = 1.0f / lrow[r];
    int tok = qb + wv * 16 + quad * 4 + r;
    for (int dt = 0; dt < 4; dt++) {
      int ch = h * 64 + dt * 16 + l16;
      val[((size_t)(b * 4096 + tok)) * 512 + ch] = o[dt][r] * inv;
    }
  }
}

// ---------------------------------------------------------------------------
// Kernel 4: post-LayerNorm + residual. out = xn + LN(val).
// ---------------------------------------------------------------------------
__global__ void post_ln_kernel(const float* __restrict__ valp, const float* __restrict__ xn,
                               const float* __restrict__ g, const float* __restrict__ be,
                               float* __restrict__ out) {
  int row = blockIdx.x;
  const float2* vr = (const float2*)(valp + (size_t)row * CC);
  float2 v = vr[threadIdx.x];
  float s  = v.x + v.y;
  float sq = v.x * v.x + v.y * v.y;
  __shared__ float sm[10];
  for (int off = 32; off; off >>= 1) {
    s  += __shfl_down(s,  off, 64);
    sq += __shfl_down(sq, off, 64);
  }
  int w = threadIdx.x >> 6;
  if ((threadIdx.x & 63) == 0) { sm[w] = s; sm[4 + w] = sq; }
  __syncthreads();
  if (threadIdx.x == 0) {
    sm[8] = sm[0] + sm[1] + sm[2] + sm[3];
    sm[9] = sm[4] + sm[5] + sm[6] + sm[7];
  }
  __syncthreads();
  float mean = sm[8] * (1.0f / CC);
  float var  = sm[9] * (1.0f / CC) - mean * mean;
  float rstd = rsqrtf(var + 1e-5f);
  int i0 = threadIdx.x * 2, i1 = i0 + 1;
  size_t base = (size_t)row * CC;
  out[base + i0] = (v.x - mean) * rstd * g[i0] + be[i0] + xn[base + i0];
  out[base + i1] = (v.y - mean) * rstd * g[i1] + be[i1] + xn[base + i1];
}

// ---------------------------------------------------------------------------
extern "C" void kernel_launch(void* const* d_in, const int* in_sizes, int n_in,
                              void* d_out, int out_size, void* d_ws, size_t ws_size,
                              hipStream_t stream) {
  const float* x       = (const float*)d_in[0];
  const float* w_qkv   = (const float*)d_in[1];
  const float* b_qkv   = (const float*)d_in[2];
  const float* g_pre   = (const float*)d_in[3];
  const float* be_pre  = (const float*)d_in[4];
  const float* g_post  = (const float*)d_in[5];
  const float* be_post = (const float*)d_in[6];
  float* out = (float*)d_out;

  // Workspace layout (bytes): xn fp32 16M | val fp32 16M | xnb bf16 8M |
  // qkv bf16 24M | wt bf16 1.5M  => ~67 MB total
  float* xn  = (float*)d_ws;
  float* val = xn + 4194304;
  unsigned short* xnb  = (unsigned short*)(val + 4194304);
  unsigned short* qkvb = xnb + 4194304;
  unsigned short* wt   = qkvb + 3 * (size_t)PS;

  convert_w_kernel<<<3072, 256, 0, stream>>>(w_qkv, wt);
  pre_ln_kernel<<<MR, 256, 0, stream>>>(x, g_pre, be_pre, xn, xnb);
  qkv_gemm_kernel<<<dim3(12, 64), 256, 0, stream>>>(xnb, wt, b_qkv, qkvb);
  attn_kernel<<<dim3(64, 16), 256, 0, stream>>>(qkvb, val);
  post_ln_kernel<<<MR, 256, 0, stream>>>(val, xn, g_post, be_post, out);
}

// Round 2
// 258.800 us; speedup vs baseline: 1.7235x; 1.7235x over previous
//
#include <hip/hip_runtime.h>

// Problem constants
#define BB   2
#define NN   4096
#define CC   512
#define HH   8
#define DD   64
#define MR   8192          // B*N rows
#define NC3  1536          // 3*C
#define PS   4194304       // per-part stride in qkv buffer = B*H*N*D

typedef __attribute__((ext_vector_type(8))) short short8;
typedef __attribute__((ext_vector_type(4))) float floatx4;

__device__ inline unsigned short f2bf(float f) {
  unsigned int u = __float_as_uint(f);
  u = (u + 0x7fffu + ((u >> 16) & 1u)) >> 16;
  return (unsigned short)u;
}

// pack two fp32 -> bf16x2 dword (round-half-up; inputs finite)
__device__ inline unsigned int pack_bf2(float a, float b) {
  unsigned int ua = __float_as_uint(a) + 0x8000u;
  unsigned int ub = __float_as_uint(b) + 0x8000u;
  return (ub & 0xffff0000u) | (ua >> 16);
}

__device__ inline floatx4 fzero4() { floatx4 z = {0.f, 0.f, 0.f, 0.f}; return z; }

// ---------------------------------------------------------------------------
// Kernel 0: convert + transpose w_qkv [512,1536] fp32 -> wt [1536,512] bf16
// ---------------------------------------------------------------------------
__global__ void convert_w_kernel(const float* __restrict__ w, unsigned short* __restrict__ wt) {
  int tid = blockIdx.x * 256 + threadIdx.x;   // [0, 1536*512)
  int n = tid >> 9;
  int k = tid & 511;
  wt[tid] = f2bf(w[k * NC3 + n]);
}

// ---------------------------------------------------------------------------
// Kernel 1: pre-LayerNorm. One block per row (C=512), 256 threads x float2.
// ---------------------------------------------------------------------------
__global__ void pre_ln_kernel(const float* __restrict__ x, const float* __restrict__ g,
                              const float* __restrict__ be, float* __restrict__ xn,
                              unsigned short* __restrict__ xnb) {
  int row = blockIdx.x;
  const float2* xr = (const float2*)(x + (size_t)row * CC);
  float2 v = xr[threadIdx.x];
  float s  = v.x + v.y;
  float sq = v.x * v.x + v.y * v.y;
  __shared__ float sm[10];
  for (int off = 32; off; off >>= 1) {
    s  += __shfl_down(s,  off, 64);
    sq += __shfl_down(sq, off, 64);
  }
  int w = threadIdx.x >> 6;
  if ((threadIdx.x & 63) == 0) { sm[w] = s; sm[4 + w] = sq; }
  __syncthreads();
  if (threadIdx.x == 0) {
    sm[8] = sm[0] + sm[1] + sm[2] + sm[3];
    sm[9] = sm[4] + sm[5] + sm[6] + sm[7];
  }
  __syncthreads();
  float mean = sm[8] * (1.0f / CC);
  float var  = sm[9] * (1.0f / CC) - mean * mean;
  float rstd = rsqrtf(var + 1e-5f);
  int i0 = threadIdx.x * 2, i1 = i0 + 1;
  float a = (v.x - mean) * rstd * g[i0] + be[i0];
  float b = (v.y - mean) * rstd * g[i1] + be[i1];
  size_t base = (size_t)row * CC;
  xn[base + i0] = a;          xn[base + i1] = b;
  xnb[base + i0] = f2bf(a);   xnb[base + i1] = f2bf(b);
}

// ---------------------------------------------------------------------------
// Kernel 2: QKV GEMM (unchanged structure). Q pre-scaled by 0.125*log2(e) so
// the attention kernel can use exp2 directly.
// ---------------------------------------------------------------------------
#define QSCALE 0.180336879f   // 0.125 * 1.44269504

__global__ __launch_bounds__(256) void qkv_gemm_kernel(
    const unsigned short* __restrict__ xnb, const unsigned short* __restrict__ wt,
    const float* __restrict__ bias, unsigned short* __restrict__ qkvb) {
  __shared__ __align__(16) short As[128][72];
  __shared__ __align__(16) short Bs[128][72];
  int tn = blockIdx.x;          // 0..11
  int tm = blockIdx.y;          // 0..63
  int tid = threadIdx.x;
  int wv = tid >> 6, lane = tid & 63;
  int quad = lane >> 4, l16 = lane & 15;
  int wm = wv >> 1, wn = wv & 1;

  floatx4 acc[4][4];
  for (int i = 0; i < 4; i++) for (int j = 0; j < 4; j++) acc[i][j] = fzero4();

  for (int k0 = 0; k0 < 512; k0 += 64) {
    for (int it = 0; it < 4; it++) {
      int c = it * 256 + tid;
      int row = c >> 3, col8 = (c & 7) * 8;
      *(uint4*)&As[row][col8] = *(const uint4*)&xnb[(size_t)(tm * 128 + row) * 512 + k0 + col8];
      *(uint4*)&Bs[row][col8] = *(const uint4*)&wt[(size_t)(tn * 128 + row) * 512 + k0 + col8];
    }
    __syncthreads();
    for (int kk = 0; kk < 64; kk += 32) {
      short8 a[4], b[4];
      for (int mt = 0; mt < 4; mt++)
        a[mt] = *(const short8*)&As[wm * 64 + mt * 16 + l16][kk + quad * 8];
      for (int nt = 0; nt < 4; nt++)
        b[nt] = *(const short8*)&Bs[wn * 64 + nt * 16 + l16][kk + quad * 8];
      for (int mt = 0; mt < 4; mt++)
        for (int nt = 0; nt < 4; nt++)
          acc[mt][nt] = __builtin_amdgcn_mfma_f32_16x16x32_bf16(a[mt], b[nt], acc[mt][nt], 0, 0, 0);
    }
    __syncthreads();
  }

  for (int mt = 0; mt < 4; mt++) {
    int gm = tm * 128 + wm * 64 + mt * 16 + quad * 4;
    int bidx = gm >> 12;
    for (int nt = 0; nt < 4; nt++) {
      int gj = tn * 128 + wn * 64 + nt * 16 + l16;
      int part = gj >> 9, cc = gj & 511;
      int h = cc >> 6, d = cc & 63;
      float bv = bias[gj];
      for (int r = 0; r < 4; r++) {
        int tok = (gm + r) & 4095;
        float v = acc[mt][nt][r] + bv;
        size_t idx;
        if (part == 0) {        // Q: [B,H,N,D], pre-scale 0.125*log2e
          v *= QSCALE;
          idx = ((size_t)((bidx * 8 + h) * 4096 + tok)) * 64 + d;
        } else if (part == 1) { // K: [B,H,N,D]
          idx = (size_t)PS + ((size_t)((bidx * 8 + h) * 4096 + tok)) * 64 + d;
        } else {                // V: [B,H,D,N]
          idx = 2 * (size_t)PS + ((size_t)((bidx * 8 + h) * 64 + d)) * 4096 + tok;
        }
        qkvb[idx] = f2bf(v);
      }
    }
  }
}

// ---------------------------------------------------------------------------
// Kernel 3: flash attention, transposed-score formulation.
//   Grid (32 q-tiles of 128, 16 bh). 256 thr = 4 waves, each wave 32 q-rows
//   (2 m-groups of 16). K-tiles of 128 keys, 32 iterations.
//   S^T = K·Q^T  (C: row=key, col=q)  -> softmax reductions mostly in-lane
//   O^T = V·P^T  (C: row=d,   col=q)  -> alpha/1/l rescale needs no shuffles
//   P passes C->B-layout via wave-private LDS slab ([q][key], b64 writes,
//   conflict-free, NO barrier needed).
// ---------------------------------------------------------------------------
// LDS carve: Ks 128x72 shorts (18432 B) | Vt 64x136 (17408 B) | Ps 4x32x136
// (34816 B). Epilogue slab (float [128][68] = 34816 B) aliases Ks+Vt.
#define SMEM_BYTES (18432 + 17408 + 34816)

__global__ __launch_bounds__(256, 2) void attn_kernel(
    const unsigned short* __restrict__ qkvb, float* __restrict__ val) {
  __shared__ __align__(16) char smem[SMEM_BYTES];
  short (*Ks)[72]  = (short (*)[72])smem;
  short (*Vt)[136] = (short (*)[136])(smem + 18432);
  short (*Psl)[136] = (short (*)[136])(smem + 18432 + 17408);  // [4*32][136]
  float (*slab)[68] = (float (*)[68])smem;

  int bh = blockIdx.y;
  int qb = blockIdx.x * 128;
  int tid = threadIdx.x;
  int wv = tid >> 6, lane = tid & 63, quad = lane >> 4, l16 = lane & 15;
  const unsigned short* Qg = qkvb + (size_t)bh * NN * DD;
  const unsigned short* Kg = qkvb + (size_t)PS + (size_t)bh * NN * DD;
  const unsigned short* Vg = qkvb + 2 * (size_t)PS + (size_t)bh * DD * NN;

  // ---- Stage Q tile (128x64) into Ks, pull B-fragments (q rows) to regs.
  for (int it = 0; it < 4; it++) {
    int c = it * 256 + tid;
    int row = c >> 3, col8 = (c & 7) * 8;
    *(uint4*)&Ks[row][col8] = *(const uint4*)&Qg[(size_t)(qb + row) * 64 + col8];
  }
  __syncthreads();
  short8 qf[2][2];
  for (int g = 0; g < 2; g++)
    for (int kk = 0; kk < 2; kk++)
      qf[g][kk] = *(const short8*)&Ks[wv * 32 + g * 16 + l16][kk * 32 + quad * 8];

  floatx4 o[2][4];
  for (int g = 0; g < 2; g++) for (int dt = 0; dt < 4; dt++) o[g][dt] = fzero4();
  float ms[2] = {-1e30f, -1e30f};
  float ls[2] = {0.0f, 0.0f};

  short* psrow0 = &Psl[wv * 32 + l16][0];         // group 0 row (q = l16)
  short* psrow1 = &Psl[wv * 32 + 16 + l16][0];    // group 1 row

  for (int kt = 0; kt < 32; kt++) {
    __syncthreads();   // previous iteration's Ks/Vt consumers done
    for (int it = 0; it < 4; it++) {
      int c = it * 256 + tid;
      int row = c >> 3, col8 = (c & 7) * 8;
      *(uint4*)&Ks[row][col8] = *(const uint4*)&Kg[(size_t)(kt * 128 + row) * 64 + col8];
      int d = c >> 4, kc8 = (c & 15) * 8;
      *(uint4*)&Vt[d][kc8] = *(const uint4*)&Vg[(size_t)d * NN + kt * 128 + kc8];
    }
    __syncthreads();

    // ---- S^T = K·Q^T : 8 key-tiles of 16. s[g][nt]: row=key(quad*4+r), col=q(l16)
    floatx4 s[2][8];
    for (int nt = 0; nt < 8; nt++) {
      short8 kf0 = *(const short8*)&Ks[nt * 16 + l16][quad * 8];
      short8 kf1 = *(const short8*)&Ks[nt * 16 + l16][32 + quad * 8];
      floatx4 s0 = fzero4(), s1 = fzero4();
      s0 = __builtin_amdgcn_mfma_f32_16x16x32_bf16(kf0, qf[0][0], s0, 0, 0, 0);
      s0 = __builtin_amdgcn_mfma_f32_16x16x32_bf16(kf1, qf[0][1], s0, 0, 0, 0);
      s1 = __builtin_amdgcn_mfma_f32_16x16x32_bf16(kf0, qf[1][0], s1, 0, 0, 0);
      s1 = __builtin_amdgcn_mfma_f32_16x16x32_bf16(kf1, qf[1][1], s1, 0, 0, 0);
      s[0][nt] = s0;
      s[1][nt] = s1;
    }

    // ---- online softmax (log2 domain; Q pre-scaled by 0.125*log2e)
    for (int g = 0; g < 2; g++) {
      float mx = -1e30f;
      for (int nt = 0; nt < 8; nt++)
        for (int r = 0; r < 4; r++) mx = fmaxf(mx, s[g][nt][r]);
      mx = fmaxf(mx, __shfl_xor(mx, 16, 64));
      mx = fmaxf(mx, __shfl_xor(mx, 32, 64));
      float mnew = fmaxf(ms[g], mx);
      float alpha = __builtin_amdgcn_exp2f(ms[g] - mnew);
      ms[g] = mnew;
      float sum = 0.0f;
      for (int nt = 0; nt < 8; nt++)
        for (int r = 0; r < 4; r++) {
          float p = __builtin_amdgcn_exp2f(s[g][nt][r] - mnew);
          s[g][nt][r] = p;
          sum += p;
        }
      sum += __shfl_xor(sum, 16, 64);
      sum += __shfl_xor(sum, 32, 64);
      ls[g] = ls[g] * alpha + sum;
      for (int dt = 0; dt < 4; dt++) o[g][dt] *= alpha;
    }

    // ---- P (C-layout, key-contiguous per lane) -> wave-private LDS [q][key]
    for (int nt = 0; nt < 8; nt++) {
      uint2 w0, w1;
      w0.x = pack_bf2(s[0][nt][0], s[0][nt][1]);
      w0.y = pack_bf2(s[0][nt][2], s[0][nt][3]);
      w1.x = pack_bf2(s[1][nt][0], s[1][nt][1]);
      w1.y = pack_bf2(s[1][nt][2], s[1][nt][3]);
      *(uint2*)&psrow0[nt * 16 + quad * 4] = w0;
      *(uint2*)&psrow1[nt * 16 + quad * 4] = w1;
    }
    // same-wave RAW through LDS: compiler inserts lgkmcnt wait; no barrier.

    // ---- O^T += V·P^T : 4 key-chunks of 32, 4 d-tiles of 16
    for (int ks = 0; ks < 4; ks++) {
      short8 pa0 = *(const short8*)&Psl[wv * 32 + l16][ks * 32 + quad * 8];
      short8 pa1 = *(const short8*)&Psl[wv * 32 + 16 + l16][ks * 32 + quad * 8];
      for (int dt = 0; dt < 4; dt++) {
        short8 vb = *(const short8*)&Vt[dt * 16 + l16][ks * 32 + quad * 8];
        o[0][dt] = __builtin_amdgcn_mfma_f32_16x16x32_bf16(vb, pa0, o[0][dt], 0, 0, 0);
        o[1][dt] = __builtin_amdgcn_mfma_f32_16x16x32_bf16(vb, pa1, o[1][dt], 0, 0, 0);
      }
    }
  }

  // ---- Epilogue: O^T/l -> slab [q_local][d] fp32 -> coalesced global write
  __syncthreads();
  for (int g = 0; g < 2; g++) {
    float inv = 1.0f / ls[g];
    int q = wv * 32 + g * 16 + l16;
    for (int dt = 0; dt < 4; dt++)
      for (int r = 0; r < 4; r++)
        slab[q][dt * 16 + quad * 4 + r] = o[g][dt][r] * inv;
  }
  __syncthreads();
  int b = bh >> 3, h = bh & 7;
  for (int it = 0; it < 8; it++) {
    int row = it * 16 + (tid >> 4);
    int col4 = (tid & 15) * 4;
    float4 vv = *(float4*)&slab[row][col4];
    *(float4*)&val[((size_t)(b * 4096 + qb + row)) * 512 + h * 64 + col4] = vv;
  }
}

// ---------------------------------------------------------------------------
// Kernel 4: post-LayerNorm + residual. out = xn + LN(val).
// ---------------------------------------------------------------------------
__global__ void post_ln_kernel(const float* __restrict__ valp, const float* __restrict__ xn,
                               const float* __restrict__ g, const float* __restrict__ be,
                               float* __restrict__ out) {
  int row = blockIdx.x;
  const float2* vr = (const float2*)(valp + (size_t)row * CC);
  float2 v = vr[threadIdx.x];
  float s  = v.x + v.y;
  float sq = v.x * v.x + v.y * v.y;
  __shared__ float sm[10];
  for (int off = 32; off; off >>= 1) {
    s  += __shfl_down(s,  off, 64);
    sq += __shfl_down(sq, off, 64);
  }
  int w = threadIdx.x >> 6;
  if ((threadIdx.x & 63) == 0) { sm[w] = s; sm[4 + w] = sq; }
  __syncthreads();
  if (threadIdx.x == 0) {
    sm[8] = sm[0] + sm[1] + sm[2] + sm[3];
    sm[9] = sm[4] + sm[5] + sm[6] + sm[7];
  }
  __syncthreads();
  float mean = sm[8] * (1.0f / CC);
  float var  = sm[9] * (1.0f / CC) - mean * mean;
  float rstd = rsqrtf(var + 1e-5f);
  int i0 = threadIdx.x * 2, i1 = i0 + 1;
  size_t base = (size_t)row * CC;
  out[base + i0] = (v.x - mean) * rstd * g[i0] + be[i0] + xn[base + i0];
  out[base + i1] = (v.y - mean) * rstd * g[i1] + be[i1] + xn[base + i1];
}

// ---------------------------------------------------------------------------
extern "C" void kernel_launch(void* const* d_in, const int* in_sizes, int n_in,
                              void* d_out, int out_size, void* d_ws, size_t ws_size,
                              hipStream_t stream) {
  const float* x       = (const float*)d_in[0];
  const float* w_qkv   = (const float*)d_in[1];
  const float* b_qkv   = (const float*)d_in[2];
  const float* g_pre   = (const float*)d_in[3];
  const float* be_pre  = (const float*)d_in[4];
  const float* g_post  = (const float*)d_in[5];
  const float* be_post = (const float*)d_in[6];
  float* out = (float*)d_out;

  float* xn  = (float*)d_ws;
  float* val = xn + 4194304;
  unsigned short* xnb  = (unsigned short*)(val + 4194304);
  unsigned short* qkvb = xnb + 4194304;
  unsigned short* wt   = qkvb + 3 * (size_t)PS;

  convert_w_kernel<<<3072, 256, 0, stream>>>(w_qkv, wt);
  pre_ln_kernel<<<MR, 256, 0, stream>>>(x, g_pre, be_pre, xn, xnb);
  qkv_gemm_kernel<<<dim3(12, 64), 256, 0, stream>>>(xnb, wt, b_qkv, qkvb);
  attn_kernel<<<dim3(32, 16), 256, 0, stream>>>(qkvb, val);
  post_ln_kernel<<<MR, 256, 0, stream>>>(val, xn, g_post, be_post, out);
}